// Round 10
// baseline (381.226 us; speedup 1.0000x reference)
//
#include <hip/hip_runtime.h>
#include <hip/hip_cooperative_groups.h>

namespace cg = cooperative_groups;

#define N_NODES 100000
#define N_EDGES 1600000
#define NEG_SLOPE 0.2f
#define LDSTRIDE 136   // 16-bit elems: 272 B rows (68 dwords ≡ 4 mod 32 banks)
#define GEMM_BLOCKS 782   // ceil(100000/128)
#define SEG_BLOCKS 1563   // ceil(400000/256) threads, 4 edges each
#define COOP_BLOCKS 768   // 3 blocks/CU x 256 CU, co-resident by construction
#define COOP_THREADS (COOP_BLOCKS * 256)

typedef __attribute__((ext_vector_type(8))) short bf16x8;
typedef __attribute__((ext_vector_type(4))) float f32x4;

__device__ __forceinline__ unsigned short f2bf(float x) {
    union { float f; unsigned u; } v; v.f = x;
    unsigned r = v.u + 0x7fffu + ((v.u >> 16) & 1u);   // RN-even
    return (unsigned short)(r >> 16);
}
__device__ __forceinline__ unsigned short f2h(float x) {
    union { _Float16 h; unsigned short u; } v; v.h = (_Float16)x;  // v_cvt_f16_f32 RNE
    return v.u;
}

// ===========================================================================
// Shared phase bodies (used by both the cooperative kernel and the fallback)
// ===========================================================================

// Wt2 prep: rows 0..127: Wt2[n][k]=bf16(W[k][n]); rows 128..135: wl/wr dots.
__device__ __forceinline__ void prep_item(
    int idx, const float* __restrict__ W, const float* __restrict__ attn_l,
    const float* __restrict__ attn_r, unsigned short* __restrict__ Wt2)
{
    if (idx >= 136 * 128) return;
    int n = idx >> 7, k = idx & 127;
    if (n < 128) {
        Wt2[idx] = f2bf(W[k * 128 + n]);
    } else {
        int h = (n - 128) & 3;
        const float* av = ((n - 128) < 4 ? attn_l : attn_r) + h * 32;
        const float* col = W + k * 128 + h * 32;
        float s = 0.f;
#pragma unroll
        for (int d2 = 0; d2 < 32; ++d2) s += col[d2] * av[d2];
        Wt2[idx] = f2bf(s);
    }
}

// seg scan item: 4 sorted-dst edges per i4.
__device__ __forceinline__ void seg_item(
    int i4, const int* __restrict__ dst, int* __restrict__ seg)
{
    const int e0 = 4 * i4;
    const int4 d = ((const int4*)dst)[i4];
    const int dp = (e0 == 0) ? -1 : dst[e0 - 1];
    for (int n = dp + 1; n <= d.x; ++n) seg[n] = e0;
    for (int n = d.x + 1; n <= d.y; ++n) seg[n] = e0 + 1;
    for (int n = d.y + 1; n <= d.z; ++n) seg[n] = e0 + 2;
    for (int n = d.z + 1; n <= d.w; ++n) seg[n] = e0 + 3;
    if (e0 + 4 == N_EDGES)
        for (int n = d.w + 1; n <= N_NODES; ++n) seg[n] = N_EDGES;
}

// One 128-node gemm tile (round-8 v3 body). B_lds: 136*LDSTRIDE ushort.
__device__ __forceinline__ void gemm_tile(
    int tile, unsigned short* B_lds, int t,
    const float* __restrict__ feat, const unsigned short* __restrict__ Wt2,
    unsigned short* __restrict__ ft, float* __restrict__ el,
    float* __restrict__ er)
{
    const int nbase = tile * 128;
    const int w = t >> 6, lane = t & 63;
    const int l15 = lane & 15, quad = lane >> 4;

    int g0 = nbase + w * 32 + l15;      if (g0 >= N_NODES) g0 = N_NODES - 1;
    int g1 = nbase + w * 32 + 16 + l15; if (g1 >= N_NODES) g1 = N_NODES - 1;
    const float4* f40 = (const float4*)feat + (size_t)g0 * 32 + quad * 2;
    const float4* f41 = (const float4*)feat + (size_t)g1 * 32 + quad * 2;
    float4 fr0[8], fr1[8];
#pragma unroll
    for (int ks = 0; ks < 4; ++ks) {
        fr0[2 * ks] = f40[ks * 8]; fr0[2 * ks + 1] = f40[ks * 8 + 1];
        fr1[2 * ks] = f41[ks * 8]; fr1[2 * ks + 1] = f41[ks * 8 + 1];
    }

    {   // stage Wt2 -> B_lds, coalesced 16B
        const int4* Wt4 = (const int4*)Wt2;
#pragma unroll
        for (int i = 0; i < 9; ++i) {
            int idx = t + 256 * i;
            if (idx < 2176) {
                int n = idx >> 4, cg2 = idx & 15;
                *(int4*)(&B_lds[n * LDSTRIDE + cg2 * 8]) = Wt4[idx];
            }
        }
    }
    __syncthreads();

    bf16x8 a0[4], a1[4];
#pragma unroll
    for (int ks = 0; ks < 4; ++ks) {
        float4 fa = fr0[2 * ks], fb = fr0[2 * ks + 1];
        a0[ks][0] = (short)f2bf(fa.x); a0[ks][1] = (short)f2bf(fa.y);
        a0[ks][2] = (short)f2bf(fa.z); a0[ks][3] = (short)f2bf(fa.w);
        a0[ks][4] = (short)f2bf(fb.x); a0[ks][5] = (short)f2bf(fb.y);
        a0[ks][6] = (short)f2bf(fb.z); a0[ks][7] = (short)f2bf(fb.w);
        fa = fr1[2 * ks]; fb = fr1[2 * ks + 1];
        a1[ks][0] = (short)f2bf(fa.x); a1[ks][1] = (short)f2bf(fa.y);
        a1[ks][2] = (short)f2bf(fa.z); a1[ks][3] = (short)f2bf(fa.w);
        a1[ks][4] = (short)f2bf(fb.x); a1[ks][5] = (short)f2bf(fb.y);
        a1[ks][6] = (short)f2bf(fb.z); a1[ks][7] = (short)f2bf(fb.w);
    }

    f32x4 acc0[9], acc1[9];
#pragma unroll
    for (int c = 0; c < 9; ++c) {
        acc0[c] = (f32x4){0.f, 0.f, 0.f, 0.f};
        acc1[c] = (f32x4){0.f, 0.f, 0.f, 0.f};
    }

    const unsigned short* Brow = &B_lds[l15 * LDSTRIDE + quad * 8];
    const unsigned short* Brow8 = &B_lds[(128 + (l15 & 7)) * LDSTRIDE + quad * 8];
#pragma unroll
    for (int ks = 0; ks < 4; ++ks) {
#pragma unroll
        for (int c = 0; c < 8; ++c) {
            bf16x8 b = *(const bf16x8*)(Brow + (c * 16) * LDSTRIDE + ks * 32);
            acc0[c] = __builtin_amdgcn_mfma_f32_16x16x32_bf16(a0[ks], b, acc0[c], 0, 0, 0);
            acc1[c] = __builtin_amdgcn_mfma_f32_16x16x32_bf16(a1[ks], b, acc1[c], 0, 0, 0);
        }
        bf16x8 b8 = *(const bf16x8*)(Brow8 + ks * 32);
        acc0[8] = __builtin_amdgcn_mfma_f32_16x16x32_bf16(a0[ks], b8, acc0[8], 0, 0, 0);
        acc1[8] = __builtin_amdgcn_mfma_f32_16x16x32_bf16(a1[ks], b8, acc1[8], 0, 0, 0);
    }

#pragma unroll
    for (int reg = 0; reg < 4; ++reg) {
        const int ga = nbase + w * 32 + quad * 4 + reg;
        if (ga < N_NODES) {
            if (l15 < 4)      el[ga * 4 + l15] = acc0[8][reg];
            else if (l15 < 8) er[ga * 4 + (l15 - 4)] = acc0[8][reg];
        }
        const int gb = ga + 16;
        if (gb < N_NODES) {
            if (l15 < 4)      el[gb * 4 + l15] = acc1[8][reg];
            else if (l15 < 8) er[gb * 4 + (l15 - 4)] = acc1[8][reg];
        }
    }

    __syncthreads();   // done reading B_lds -> reuse as ft scratch
#pragma unroll
    for (int c = 0; c < 8; ++c) {
#pragma unroll
        for (int reg = 0; reg < 4; ++reg) {
            B_lds[(w * 32 + quad * 4 + reg) * LDSTRIDE + c * 16 + l15] =
                f2h(acc0[c][reg]);
            B_lds[(w * 32 + 16 + quad * 4 + reg) * LDSTRIDE + c * 16 + l15] =
                f2h(acc1[c][reg]);
        }
    }
    __syncthreads();

#pragma unroll
    for (int i = 0; i < 8; ++i) {
        int idx = t + 256 * i;
        int node = idx >> 4, cg2 = idx & 15;
        int gg = nbase + node;
        if (gg < N_NODES) {
            int4 val = *(const int4*)(&B_lds[node * LDSTRIDE + cg2 * 8]);
            *(int4*)(&ft[(size_t)gg * 128 + cg2 * 8]) = val;
        }
    }
}

// One node's aggregation (round-8 floor core + NT out stores). node<N_NODES.
__device__ __forceinline__ void agg_node(
    int node, int lane,
    const unsigned short* __restrict__ ft, const float* __restrict__ el,
    const float* __restrict__ er, const int* __restrict__ src,
    const int* __restrict__ seg, float* __restrict__ out)
{
    const int qt = lane >> 4;
    const int l15 = lane & 15;
    const int hf = l15 >> 2;

    const int beg = __builtin_amdgcn_readfirstlane(seg[node]);
    const int end = __builtin_amdgcn_readfirstlane(seg[node + 1]);
    const float er_h = er[node * 4 + hf];

    float dpart = 0.f;
    float4 accA = make_float4(0.f, 0.f, 0.f, 0.f);
    float4 accB = make_float4(0.f, 0.f, 0.f, 0.f);

    for (int c0 = beg; c0 < end; c0 += 16) {
        const int cb = c0 + 4 * qt;
        int s4[4];
#pragma unroll
        for (int k = 0; k < 4; ++k) {
            int ci = cb + k;
            s4[k] = src[ci < end ? ci : end - 1];
        }
        float ev[4];
#pragma unroll
        for (int k = 0; k < 4; ++k) ev[k] = el[s4[k] * 4 + hf];
        float p[4];
#pragma unroll
        for (int k = 0; k < 4; ++k) {
            float e = ev[k] + er_h;
            e = (e > 0.f) ? e : NEG_SLOPE * e;
            p[k] = (cb + k < end) ? __expf(e) : 0.f;
            dpart += p[k];
        }
        uint4 v[4];
#pragma unroll
        for (int k = 0; k < 4; ++k)
            v[k] = *(const uint4*)(ft + (((size_t)(unsigned)s4[k]) << 7) + l15 * 8);
#pragma unroll
        for (int k = 0; k < 4; ++k) {
            const float pj = p[k];
            asm("v_fma_mix_f32 %0, %2, %3, %0 op_sel_hi:[1,0,0]\n\t"
                "v_fma_mix_f32 %1, %2, %3, %1 op_sel:[1,0,0] op_sel_hi:[1,0,0]"
                : "+v"(accA.x), "+v"(accA.y) : "v"(v[k].x), "v"(pj));
            asm("v_fma_mix_f32 %0, %2, %3, %0 op_sel_hi:[1,0,0]\n\t"
                "v_fma_mix_f32 %1, %2, %3, %1 op_sel:[1,0,0] op_sel_hi:[1,0,0]"
                : "+v"(accA.z), "+v"(accA.w) : "v"(v[k].y), "v"(pj));
            asm("v_fma_mix_f32 %0, %2, %3, %0 op_sel_hi:[1,0,0]\n\t"
                "v_fma_mix_f32 %1, %2, %3, %1 op_sel:[1,0,0] op_sel_hi:[1,0,0]"
                : "+v"(accB.x), "+v"(accB.y) : "v"(v[k].z), "v"(pj));
            asm("v_fma_mix_f32 %0, %2, %3, %0 op_sel_hi:[1,0,0]\n\t"
                "v_fma_mix_f32 %1, %2, %3, %1 op_sel:[1,0,0] op_sel_hi:[1,0,0]"
                : "+v"(accB.z), "+v"(accB.w) : "v"(v[k].w), "v"(pj));
        }
    }

    dpart  += __shfl_xor(dpart, 16);
    accA.x += __shfl_xor(accA.x, 16); accA.y += __shfl_xor(accA.y, 16);
    accA.z += __shfl_xor(accA.z, 16); accA.w += __shfl_xor(accA.w, 16);
    accB.x += __shfl_xor(accB.x, 16); accB.y += __shfl_xor(accB.y, 16);
    accB.z += __shfl_xor(accB.z, 16); accB.w += __shfl_xor(accB.w, 16);
    dpart  += __shfl_xor(dpart, 32);
    accA.x += __shfl_xor(accA.x, 32); accA.y += __shfl_xor(accA.y, 32);
    accA.z += __shfl_xor(accA.z, 32); accA.w += __shfl_xor(accA.w, 32);
    accB.x += __shfl_xor(accB.x, 32); accB.y += __shfl_xor(accB.y, 32);
    accB.z += __shfl_xor(accB.z, 32); accB.w += __shfl_xor(accB.w, 32);

    const float inv = (dpart > 0.f) ? 1.f / dpart : 0.f;

    if (qt == 0) {
        f32x4 o0 = {accA.x * inv, accA.y * inv, accA.z * inv, accA.w * inv};
        f32x4 o1 = {accB.x * inv, accB.y * inv, accB.z * inv, accB.w * inv};
        float* op = out + (size_t)node * 128 + l15 * 8;
        __builtin_nontemporal_store(o0, (f32x4*)op);
        __builtin_nontemporal_store(o1, (f32x4*)(op + 4));
    }
}

// ===========================================================================
// Cooperative single-dispatch kernel: prep+seg -> sync -> gemm -> sync -> agg
// 768 blocks x 256 thr, 3 blocks/CU co-resident. Bounds the ENTIRE device
// work in one profiled dispatch (tests the unattributed ~85 us directly).
// ===========================================================================
__global__ __launch_bounds__(256, 3) void fused_kernel(
    const float* __restrict__ feat, const int* __restrict__ src,
    const int* __restrict__ dst, const float* __restrict__ W,
    const float* __restrict__ attn_l, const float* __restrict__ attn_r,
    float* __restrict__ out, unsigned short* __restrict__ ft,
    float* __restrict__ el, float* __restrict__ er,
    unsigned short* __restrict__ Wt2, int* __restrict__ seg)
{
    __shared__ __align__(16) unsigned short B_lds[136 * LDSTRIDE];  // 36992 B
    cg::grid_group grid = cg::this_grid();
    const int t = threadIdx.x;
    const int gtid = blockIdx.x * 256 + t;

    // ---- phase A: Wt2 prep + seg scan ----
    prep_item(gtid, W, attn_l, attn_r, Wt2);
    for (int i4 = gtid; i4 < N_EDGES / 4; i4 += COOP_THREADS)
        seg_item(i4, dst, seg);
    grid.sync();

    // ---- phase B: gemm tiles, grid-stride ----
    for (int tile = blockIdx.x; tile < GEMM_BLOCKS; tile += COOP_BLOCKS) {
        gemm_tile(tile, B_lds, t, feat, Wt2, ft, el, er);
        __syncthreads();   // B_lds reuse across tiles
    }
    grid.sync();

    // ---- phase C: aggregation, grid-stride (1 node/wave/iter) ----
    const int wv = t >> 6, lane = t & 63;
    for (int it = blockIdx.x; it < N_NODES / 4; it += COOP_BLOCKS)
        agg_node(it * 4 + wv, lane, ft, el, er, src, seg, out);
}

// ===========================================================================
// Fallback (round-8 3-dispatch path), used if cooperative launch is rejected
// ===========================================================================
__global__ __launch_bounds__(256) void fb_prep_seg_kernel(
    const int* __restrict__ dst, int* __restrict__ seg,
    const float* __restrict__ W, const float* __restrict__ attn_l,
    const float* __restrict__ attn_r, unsigned short* __restrict__ Wt2)
{
    const int b = blockIdx.x;
    if (b < SEG_BLOCKS) {
        int i4 = b * 256 + threadIdx.x;
        if (i4 < N_EDGES / 4) seg_item(i4, dst, seg);
    } else {
        prep_item((b - SEG_BLOCKS) * 256 + threadIdx.x, W, attn_l, attn_r, Wt2);
    }
}

__global__ __launch_bounds__(256, 3) void fb_gemm_kernel(
    const float* __restrict__ feat, const unsigned short* __restrict__ Wt2,
    unsigned short* __restrict__ ft, float* __restrict__ el,
    float* __restrict__ er)
{
    __shared__ __align__(16) unsigned short B_lds[136 * LDSTRIDE];
    gemm_tile(blockIdx.x, B_lds, threadIdx.x, feat, Wt2, ft, el, er);
}

__global__ __launch_bounds__(256) void fb_aggregate_kernel(
    const unsigned short* __restrict__ ft, const float* __restrict__ el,
    const float* __restrict__ er, const int* __restrict__ src,
    const int* __restrict__ seg, float* __restrict__ out)
{
    const int node = blockIdx.x * 4 + (threadIdx.x >> 6);
    if (node >= N_NODES) return;
    agg_node(node, threadIdx.x & 63, ft, el, er, src, seg, out);
}

// ---------------------------------------------------------------------------
extern "C" void kernel_launch(void* const* d_in, const int* in_sizes, int n_in,
                              void* d_out, int out_size, void* d_ws, size_t ws_size,
                              hipStream_t stream) {
    const float* feat   = (const float*)d_in[0];
    const int*   src    = (const int*)d_in[1];
    const int*   dst    = (const int*)d_in[2];
    const float* W      = (const float*)d_in[3];
    const float* attn_l = (const float*)d_in[4];
    const float* attn_r = (const float*)d_in[5];
    float* out = (float*)d_out;

    unsigned short* ft = (unsigned short*)d_ws;               // 12.8M fp16
    float* el  = (float*)(ft + (size_t)12800000);
    float* er  = el + 400000;
    unsigned short* Wt2 = (unsigned short*)(er + 400000);     // 136*128 bf16
    int* seg = (int*)(Wt2 + 136 * 128);                       // 100001 int

    void* args[] = {
        (void*)&feat, (void*)&src, (void*)&dst, (void*)&W,
        (void*)&attn_l, (void*)&attn_r, (void*)&out, (void*)&ft,
        (void*)&el, (void*)&er, (void*)&Wt2, (void*)&seg,
    };
    hipError_t err = hipLaunchCooperativeKernel(
        (const void*)fused_kernel, dim3(COOP_BLOCKS), dim3(256), args, 0, stream);
    if (err != hipSuccess) {
        (void)hipGetLastError();   // clear sticky error; run fallback path
        fb_prep_seg_kernel<<<SEG_BLOCKS + 68, 256, 0, stream>>>(
            dst, seg, W, attn_l, attn_r, Wt2);
        fb_gemm_kernel<<<GEMM_BLOCKS, 256, 0, stream>>>(feat, Wt2, ft, el, er);
        fb_aggregate_kernel<<<(N_NODES + 3) / 4, 256, 0, stream>>>(
            ft, el, er, src, seg, out);
    }
}